// Round 18
// baseline (181.332 us; speedup 1.0000x reference)
//
#include <hip/hip_runtime.h>
#include <stdint.h>

typedef __bf16 bf16x8 __attribute__((ext_vector_type(8)));
typedef float f32x4 __attribute__((ext_vector_type(4)));
typedef unsigned short ushort_t;
typedef unsigned int uint_t;

__device__ inline ushort_t f2bf(float f) {
  uint_t u = __builtin_bit_cast(uint_t, f);
  u = (u + 0x7FFFu + ((u >> 16) & 1u)) >> 16;
  return (ushort_t)u;
}

// async global->LDS, 16B per lane. LDS dest must be wave-uniform base; HW adds lane*16.
__device__ inline void gll16(const void* g, void* l) {
  __builtin_amdgcn_global_load_lds(
      (__attribute__((address_space(1))) void*)(uintptr_t)g,
      (__attribute__((address_space(3))) void*)(uint32_t)(uintptr_t)l,
      16, 0, 0);
}

// One launch: x (2M float4) then Wq|Wk|Wv|Wo (4 x 256K float4). Wq scaled.
__global__ void cast_all(const float* __restrict__ x, const float* __restrict__ w0,
                         const float* __restrict__ w1, const float* __restrict__ w2,
                         const float* __restrict__ w3, ushort_t* __restrict__ xb,
                         ushort_t* __restrict__ wc, float s0) {
  const int i = blockIdx.x * 256 + threadIdx.x;  // 0 .. 3M-1 float4 units
  const float* src;
  ushort_t* dst;
  float sc = 1.0f;
  int j;
  if (i < (1 << 21)) {  // x: 8192*1024 floats = 2M float4
    src = x;
    dst = xb;
    j = i;
  } else {
    const int k = i - (1 << 21);
    const int which = k >> 18;
    src = which == 0 ? w0 : which == 1 ? w1 : which == 2 ? w2 : w3;
    if (which == 0) sc = s0;
    dst = wc + (k >> 18) * (1 << 20);
    j = k & 0x3FFFF;
  }
  float4 v = reinterpret_cast<const float4*>(src)[j];
  ushort4 o;
  o.x = f2bf(v.x * sc);
  o.y = f2bf(v.y * sc);
  o.z = f2bf(v.z * sc);
  o.w = f2bf(v.w * sc);
  reinterpret_cast<ushort4*>(dst)[j] = o;
}

// ---------------- 8-wave GEMM template (R17: 1-barrier overlap schedule)
#define MFMA16(A_, B_, C_) __builtin_amdgcn_mfma_f32_16x16x32_bf16(A_, B_, C_, 0, 0, 0)
#define SBAR __builtin_amdgcn_s_barrier
#define SCHED0 __builtin_amdgcn_sched_barrier(0)

template <int MF, int NF, int NTN, int LDC, bool F32OUT>
__global__ __launch_bounds__(512, 2) void gemm8p(const ushort_t* __restrict__ A,
                                                 const ushort_t* __restrict__ B,
                                                 void* __restrict__ C) {
  constexpr int BM = MF * 32;
  constexpr int BN = NF * 64;
  constexpr int NA = BM / 64;
  constexpr int NB = BN / 64;
  constexpr int AU = BM * 64;
  constexpr int BUF = AU + BN * 64;
  constexpr int NWG = (8192 / BM) * NTN;
  __shared__ __attribute__((aligned(16))) ushort_t smem[2 * BUF];

  const int tid = threadIdx.x;
  const int lane = tid & 63;
  const int w = tid >> 6;
  const int wm = w >> 2, wn = w & 3;

  const int bid = blockIdx.x;
  const int swz = (bid & 7) * (NWG / 8) + (bid >> 3);
  const int m0 = (swz / NTN) * BM;
  const int n0 = (swz % NTN) * BN;

  const int scol = ((tid & 7) ^ ((tid >> 3) & 7)) * 8;
  const ushort_t* gA = A + (size_t)(m0 + (tid >> 3)) * 1024 + scol;
  const ushort_t* gB = B + (size_t)(n0 + (tid >> 3)) * 1024 + scol;

  const int lr = lane & 15;
  const int hi = lane >> 4;
  const int arow = (wm * MF * 16 + lr) * 64;
  const int brow = AU + (wn * NF * 16 + lr) * 64;
  const int cx0 = (hi * 8) ^ ((lane & 7) << 3);
  const int cx1 = cx0 ^ 32;

  f32x4 acc[MF][NF] = {};
  bf16x8 a0[MF / 2][2], a1[MF / 2][2];
  bf16x8 b[NF][2];

  auto stage_all = [&](int wbu, int sk) __attribute__((always_inline)) {
#pragma unroll
    for (int i = 0; i < NA; ++i)
      gll16(gA + i * 65536 + sk, &smem[wbu + i * 4096 + (w << 9)]);
#pragma unroll
    for (int i = 0; i < NB; ++i)
      gll16(gB + i * 65536 + sk, &smem[wbu + AU + i * 4096 + (w << 9)]);
  };
  auto rdA = [&](int rbu, int mbase, bf16x8(&aa)[MF / 2][2])
      __attribute__((always_inline)) {
#pragma unroll
    for (int m = 0; m < MF / 2; ++m) {
      const int base = rbu + arow + (mbase + m) * 1024;
      aa[m][0] = *(const bf16x8*)&smem[base + cx0];
      aa[m][1] = *(const bf16x8*)&smem[base + cx1];
    }
  };
  auto rdBall = [&](int rbu) __attribute__((always_inline)) {
#pragma unroll
    for (int n = 0; n < NF; ++n) {
      const int base = rbu + brow + n * 1024;
      b[n][0] = *(const bf16x8*)&smem[base + cx0];
      b[n][1] = *(const bf16x8*)&smem[base + cx1];
    }
  };
  auto mmH = [&](int mbase, bf16x8(&aa)[MF / 2][2]) __attribute__((always_inline)) {
#pragma unroll
    for (int m = 0; m < MF / 2; ++m)
#pragma unroll
      for (int n = 0; n < NF; ++n) {
        acc[mbase + m][n] = MFMA16(aa[m][0], b[n][0], acc[mbase + m][n]);
        acc[mbase + m][n] = MFMA16(aa[m][1], b[n][1], acc[mbase + m][n]);
      }
  };

  auto tile = [&](int rbu, int wbu, int sk, bool pf) __attribute__((always_inline)) {
    rdA(rbu, 0, a0);
    rdBall(rbu);
    if (pf) stage_all(wbu, sk);
    rdA(rbu, MF / 2, a1);
    SCHED0;
    __builtin_amdgcn_s_setprio(1);
    mmH(0, a0);
    __builtin_amdgcn_s_setprio(0);
    SCHED0;
    __builtin_amdgcn_s_setprio(1);
    mmH(MF / 2, a1);
    __builtin_amdgcn_s_setprio(0);
    SCHED0;
    if (pf) asm volatile("s_waitcnt vmcnt(0)" ::: "memory");
    SBAR();
    SCHED0;
  };

  stage_all(0, 0);
  asm volatile("s_waitcnt vmcnt(0)" ::: "memory");
  SBAR();
  SCHED0;
  int sk = 64;
  for (int it = 0; it < 7; ++it) {
    tile(0, BUF, sk, true);
    sk += 64;
    tile(BUF, 0, sk, true);
    sk += 64;
  }
  tile(0, BUF, sk, true);
  tile(BUF, 0, 0, false);

  const size_t erow = (size_t)(m0 + wm * MF * 16 + hi * 4);
  const int ecol = n0 + wn * NF * 16 + lr;
#pragma unroll
  for (int mf = 0; mf < MF; ++mf)
#pragma unroll
    for (int nf = 0; nf < NF; ++nf)
#pragma unroll
      for (int r = 0; r < 4; ++r) {
        const size_t idx = (erow + mf * 16 + r) * LDC + ecol + nf * 16;
        if constexpr (F32OUT)
          ((float*)C)[idx] = acc[mf][nf][r];
        else
          ((ushort_t*)C)[idx] = f2bf(acc[mf][nf][r]);
      }
}

// Causal flash attention. QKV [8192,3072] bf16 (Q|K|V), Q pre-scaled by 0.125*log2(e).
// R18: 8-wave blocks — waves 0-3 own group B (qt=7-p) row-slices, waves 4-7 own
// group A (qt=p). K/V staged once per block-tile (512-thread maps), amortized over
// 8 waves; one group per wave halves live state -> VGPR<=128 -> 4 waves/SIMD.
// V slot-permuted (R16) so PV A-frag assembles from cvt_pk outputs directly.
__global__ __launch_bounds__(512, 4) void attn_fwd(const ushort_t* __restrict__ QKV,
                                                   ushort_t* __restrict__ ctx) {
  const int bid = blockIdx.x;
  const int h = bid & 15;
  const int b = (bid >> 4) & 7;
  const int p = bid >> 7;  // 0..3
  const int tid = threadIdx.x;
  const int lane = tid & 63;
  const int w = tid >> 6;  // 0..7
  const int lr = lane & 15;
  const int lg = lane >> 4;
  const int dk = lg << 3;

  __shared__ __attribute__((aligned(16))) ushort_t Ks[2][64 * 72];
  __shared__ __attribute__((aligned(16))) uint_t VtDw[2][64 * 36];

  // 512-thread staging maps. K: 16B/thread (row=tid>>3, 8 dims). V: 2 keys x 4 dims.
  const int krow = tid >> 3, kd8 = (tid & 7) << 3;
  const int vkp = tid & 31, vdg = tid >> 5;  // vdg 0..15
  const int pkp = ((vkp >> 4) << 4) | (((vkp >> 1) & 3) << 2) |
                  (((vkp >> 3) & 1) << 1) | (vkp & 1);
  const ushort_t* kgbase =
      QKV + ((size_t)(b * 1024 + krow)) * 3072 + 1024 + h * 64 + kd8;
  const ushort_t* vgbase =
      QKV + ((size_t)(b * 1024 + 2 * vkp)) * 3072 + 2048 + h * 64 + vdg * 4;

  const float FMAX2 = 23.083120654223414f;  // 16 * log2(e)

  const int qtA = p, qtB = 7 - p;
  const int ntB = (qtB + 1) << 1;
  const int qt = (w >> 2) ? qtA : qtB;  // waves 0-3: B (long); 4-7: A (short)
  const int wrow0 = (qt << 7) + (w & 3) * 32;

  bf16x8 qf[2][2];
#pragma unroll
  for (int i = 0; i < 2; ++i) {
    const ushort_t* qp =
        QKV + ((size_t)(b * 1024 + wrow0 + i * 16 + lr)) * 3072 + h * 64 + dk;
    qf[i][0] = *reinterpret_cast<const bf16x8*>(qp);
    qf[i][1] = *reinterpret_cast<const bf16x8*>(qp + 32);
  }

  f32x4 o[2][4] = {};
  float ls[2] = {0.f, 0.f};

  uint4 rk = *reinterpret_cast<const uint4*>(kgbase);
  uint2 rva = *reinterpret_cast<const uint2*>(vgbase);
  uint2 rvb = *reinterpret_cast<const uint2*>(vgbase + 3072);

  for (int t = 0; t < ntB; ++t) {
    const int bsel = t & 1;
    // ---- staging: regs (loaded last iter) -> LDS buf[t&1]
    asm volatile("s_waitcnt vmcnt(0)" ::: "memory");
    *reinterpret_cast<uint4*>(&Ks[bsel][krow * 72 + kd8]) = rk;
    {
      const ushort_t* ea = reinterpret_cast<const ushort_t*>(&rva);
      const ushort_t* eb = reinterpret_cast<const ushort_t*>(&rvb);
#pragma unroll
      for (int j = 0; j < 4; ++j)
        VtDw[bsel][(vdg * 4 + j) * 36 + pkp] = (uint_t)ea[j] | ((uint_t)eb[j] << 16);
    }
    if (t + 1 < ntB) {
      const size_t off = (size_t)(t + 1) * 64 * 3072;
      rk = *reinterpret_cast<const uint4*>(kgbase + off);
      rva = *reinterpret_cast<const uint2*>(vgbase + off);
      rvb = *reinterpret_cast<const uint2*>(vgbase + off + 3072);
    }
    asm volatile("s_waitcnt lgkmcnt(0)" ::: "memory");
    __builtin_amdgcn_s_barrier();

    const int kb = t << 6;
    if (kb <= wrow0 + 31) {
      // ---- QK^T swapped: f-outer keeps kf register window small (8 regs)
      f32x4 s[2][4];
      __builtin_amdgcn_s_setprio(1);
#pragma unroll
      for (int f = 0; f < 4; ++f) {
        const bf16x8 kf0 =
            *reinterpret_cast<const bf16x8*>(&Ks[bsel][(f * 16 + lr) * 72 + dk]);
        const bf16x8 kf1 =
            *reinterpret_cast<const bf16x8*>(&Ks[bsel][(f * 16 + lr) * 72 + 32 + dk]);
#pragma unroll
        for (int i = 0; i < 2; ++i) {
          f32x4 z = {0.f, 0.f, 0.f, 0.f};
          z = __builtin_amdgcn_mfma_f32_16x16x32_bf16(kf0, qf[i][0], z, 0, 0, 0);
          s[i][f] = __builtin_amdgcn_mfma_f32_16x16x32_bf16(kf1, qf[i][1], z, 0, 0, 0);
        }
      }
      __builtin_amdgcn_s_setprio(0);
      // ---- V fragments once per tile (shared by both row-frags)
      bf16x8 vb[2][4];
#pragma unroll
      for (int kblk = 0; kblk < 2; ++kblk)
#pragma unroll
        for (int fh = 0; fh < 4; ++fh)
          vb[kblk][fh] = *reinterpret_cast<const bf16x8*>(
              &VtDw[bsel][(fh * 16 + lr) * 36 + kblk * 16 + (lg << 2)]);
      const bool needmask = (kb + 63 > wrow0);
#pragma unroll
      for (int i = 0; i < 2; ++i) {
        const int qr = wrow0 + i * 16 + lr;
        uint_t d0[4], d1[4];
#pragma unroll
        for (int f = 0; f < 4; ++f) {
          const int kbase = kb + f * 16 + (lg << 2);
          float p0 = __builtin_amdgcn_exp2f(s[i][f][0] - FMAX2);
          float p1 = __builtin_amdgcn_exp2f(s[i][f][1] - FMAX2);
          float p2 = __builtin_amdgcn_exp2f(s[i][f][2] - FMAX2);
          float p3 = __builtin_amdgcn_exp2f(s[i][f][3] - FMAX2);
          if (needmask) {
            p0 = (kbase + 0 <= qr) ? p0 : 0.f;
            p1 = (kbase + 1 <= qr) ? p1 : 0.f;
            p2 = (kbase + 2 <= qr) ? p2 : 0.f;
            p3 = (kbase + 3 <= qr) ? p3 : 0.f;
          }
          ls[i] += (p0 + p1) + (p2 + p3);
          asm("v_cvt_pk_bf16_f32 %0, %1, %2" : "=v"(d0[f]) : "v"(p0), "v"(p1));
          asm("v_cvt_pk_bf16_f32 %0, %1, %2" : "=v"(d1[f]) : "v"(p2), "v"(p3));
        }
        __builtin_amdgcn_s_setprio(1);
#pragma unroll
        for (int kblk = 0; kblk < 2; ++kblk) {
          uint4 paw;
          paw.x = d0[2 * kblk];
          paw.y = d1[2 * kblk];
          paw.z = d0[2 * kblk + 1];
          paw.w = d1[2 * kblk + 1];
          const bf16x8 pa = __builtin_bit_cast(bf16x8, paw);
#pragma unroll
          for (int fh = 0; fh < 4; ++fh)
            o[i][fh] = __builtin_amdgcn_mfma_f32_16x16x32_bf16(pa, vb[kblk][fh],
                                                               o[i][fh], 0, 0, 0);
        }
        __builtin_amdgcn_s_setprio(0);
      }
    }
  }

  // ---- epilogue: one group per wave
#pragma unroll
  for (int i = 0; i < 2; ++i) {
    float s = ls[i];
    s += __shfl_xor(s, 16);
    s += __shfl_xor(s, 32);
    const float linv = 1.0f / s;
    const size_t crow = (size_t)(b * 1024 + wrow0 + i * 16 + (lg << 2));
#pragma unroll
    for (int r = 0; r < 4; ++r) {
      const float li = __shfl(linv, (lg << 2) + r);
#pragma unroll
      for (int fh = 0; fh < 4; ++fh)
        ctx[(crow + r) * 1024 + h * 64 + fh * 16 + lr] = f2bf(o[i][fh][r] * li);
    }
  }
}

extern "C" void kernel_launch(void* const* d_in, const int* in_sizes, int n_in,
                              void* d_out, int out_size, void* d_ws, size_t ws_size,
                              hipStream_t stream) {
  const float* x = (const float*)d_in[0];
  const float* Wk = (const float*)d_in[1];
  const float* Wq = (const float*)d_in[2];
  const float* Wv = (const float*)d_in[3];
  const float* Wo = (const float*)d_in[4];

  char* ws = (char*)d_ws;
  ushort_t* xb = (ushort_t*)ws;                  // [8192,1024] bf16 (reused as ctx)
  ushort_t* Wc = (ushort_t*)(ws + (16u << 20));  // Wq*0.125*log2e | Wk | Wv | Wo
  ushort_t* Wob = Wc + 3u * 1024 * 1024;
  ushort_t* QKV = (ushort_t*)(ws + (24u << 20));  // [8192,3072] bf16
  ushort_t* ctx = xb;

  // All casts in one launch: 3M float4 units.
  cast_all<<<12288, 256, 0, stream>>>(x, Wq, Wk, Wv, Wo, xb, Wc,
                                      0.125f * 1.4426950408889634f);

  // QKV: BM=256, BN=192 (R12 geometry + R17 overlap schedule).
  gemm8p<8, 3, 16, 3072, false><<<512, 512, 0, stream>>>(xb, Wc, QKV);

  attn_fwd<<<512, 512, 0, stream>>>(QKV, ctx);

  // Out-proj: BM=128, BN=128 (R14 geometry + R17 overlap schedule).
  gemm8p<4, 2, 8, 1024, true><<<512, 512, 0, stream>>>(ctx, Wob, (float*)d_out);
}

// Round 19
// 129.262 us; speedup vs baseline: 1.4028x; 1.4028x over previous
//
#include <hip/hip_runtime.h>
#include <stdint.h>

typedef __bf16 bf16x8 __attribute__((ext_vector_type(8)));
typedef float f32x4 __attribute__((ext_vector_type(4)));
typedef unsigned short ushort_t;
typedef unsigned int uint_t;

__device__ inline ushort_t f2bf(float f) {
  uint_t u = __builtin_bit_cast(uint_t, f);
  u = (u + 0x7FFFu + ((u >> 16) & 1u)) >> 16;
  return (ushort_t)u;
}

// async global->LDS, 16B per lane. LDS dest must be wave-uniform base; HW adds lane*16.
__device__ inline void gll16(const void* g, void* l) {
  __builtin_amdgcn_global_load_lds(
      (__attribute__((address_space(1))) void*)(uintptr_t)g,
      (__attribute__((address_space(3))) void*)(uint32_t)(uintptr_t)l,
      16, 0, 0);
}

// One launch: x (2M float4) then Wq|Wk|Wv|Wo (4 x 256K float4). Wq scaled.
__global__ void cast_all(const float* __restrict__ x, const float* __restrict__ w0,
                         const float* __restrict__ w1, const float* __restrict__ w2,
                         const float* __restrict__ w3, ushort_t* __restrict__ xb,
                         ushort_t* __restrict__ wc, float s0) {
  const int i = blockIdx.x * 256 + threadIdx.x;
  const float* src;
  ushort_t* dst;
  float sc = 1.0f;
  int j;
  if (i < (1 << 21)) {
    src = x;
    dst = xb;
    j = i;
  } else {
    const int k = i - (1 << 21);
    const int which = k >> 18;
    src = which == 0 ? w0 : which == 1 ? w1 : which == 2 ? w2 : w3;
    if (which == 0) sc = s0;
    dst = wc + (k >> 18) * (1 << 20);
    j = k & 0x3FFFF;
  }
  float4 v = reinterpret_cast<const float4*>(src)[j];
  ushort4 o;
  o.x = f2bf(v.x * sc);
  o.y = f2bf(v.y * sc);
  o.z = f2bf(v.z * sc);
  o.w = f2bf(v.w * sc);
  reinterpret_cast<ushort4*>(dst)[j] = o;
}

// ---------------- 8-wave GEMM, R19: per-UNIT counted-vmcnt pipeline (m201-style).
// Stage units {uA1, uB0, uBr, uA2} with INTERLEAVED physical row maps so phase-k
// reads (all waves) live in unit k. Per-phase: reads (post-prev-barrier, unit
// confirmed) -> stage next unit -> counted vmcnt (confirm unit for next phase)
// -> SBAR -> lgkm0 -> MFMA -> SBAR. vmcnt never 0 mid-loop; FIFO hand-derived.
#define MFMA16(A_, B_, C_) __builtin_amdgcn_mfma_f32_16x16x32_bf16(A_, B_, C_, 0, 0, 0)
#define SBAR __builtin_amdgcn_s_barrier
#define SCHED0 __builtin_amdgcn_sched_barrier(0)
#define LGKM0 asm volatile("s_waitcnt lgkmcnt(0)" ::: "memory")
#define VMC(n) asm volatile("s_waitcnt vmcnt(" #n ")" ::: "memory")

template <int MF, int NF, int NTN, int LDC, bool F32OUT>
__global__ __launch_bounds__(512, 2) void gemm8p(const ushort_t* __restrict__ A,
                                                 const ushort_t* __restrict__ B,
                                                 void* __restrict__ C) {
  constexpr int BM = MF * 32;
  constexpr int BN = NF * 64;
  constexpr int NA = BM / 64;   // A loads/thread/tile (4 or 2)
  constexpr int NAH = NA / 2;   // per A-half unit
  constexpr int NBR = NF - 1;   // B-rest loads
  constexpr int QA = BM / 4;
  constexpr int AU = BM * 64;
  constexpr int BUF = AU + BN * 64;
  constexpr int NWG = (8192 / BM) * NTN;
  __shared__ __attribute__((aligned(16))) ushort_t smem[2 * BUF];

  const int tid = threadIdx.x;
  const int lane = tid & 63;
  const int w = tid >> 6;
  const int wm = w >> 2, wn = w & 3;

  const int bid = blockIdx.x;
  const int swz = (bid & 7) * (NWG / 8) + (bid >> 3);
  const int m0 = (swz / NTN) * BM;
  const int n0 = (swz % NTN) * BN;

  // staging maps: thread covers phys row prow=(tid>>3), chunk (tid&7); source col
  // pre-swizzled (same involution both sides; all row maps ≡ lr mod 8).
  const int prow = tid >> 3;
  const int scol = ((tid & 7) ^ (prow & 7)) * 8;
  const ushort_t* gA0 = A + (size_t)m0 * 1024 + scol;
  const ushort_t* gB0 = B + (size_t)n0 * 1024 + scol;

  // A load i -> phys rows i*64+prow; global row via interleaved half map.
  int arow_ld[NA];
#pragma unroll
  for (int i = 0; i < NA; ++i) {
    const int half = (i >= NAH) ? 1 : 0;
    const int p = (i - half * NAH) * 64 + prow;
    arow_ld[i] = (p / QA) * (BM / 2) + half * QA + (p % QA);
  }
  const int brow0 = (prow >> 4) * (BN / 4) + (prow & 15);  // uB0: n0 frag rows
  int browr_ld[(NBR > 0) ? NBR : 1];
#pragma unroll
  for (int j = 0; j < NBR; ++j) {
    const int p = j * 64 + prow;
    constexpr int R = (NF - 1) * 16;
    browr_ld[j] = (p / R) * (NF * 16) + 16 + (p % R);
  }

  const int lr = lane & 15;
  const int hi = lane >> 4;
  const int cx0 = (hi * 8) ^ ((lane & 7) << 3);
  const int cx1 = cx0 ^ 32;

  f32x4 acc[MF][NF] = {};
  bf16x8 a0[MF / 2][2], a1[MF / 2][2];
  bf16x8 b[NF][2];

  auto stage_uA1 = [&](int wbu, int sk) __attribute__((always_inline)) {
#pragma unroll
    for (int i = 0; i < NAH; ++i)
      gll16(gA0 + (size_t)arow_ld[i] * 1024 + sk, &smem[wbu + i * 4096 + (w << 9)]);
  };
  auto stage_uA2 = [&](int wbu, int sk) __attribute__((always_inline)) {
#pragma unroll
    for (int i = NAH; i < NA; ++i)
      gll16(gA0 + (size_t)arow_ld[i] * 1024 + sk, &smem[wbu + i * 4096 + (w << 9)]);
  };
  auto stage_uB0 = [&](int wbu, int sk) __attribute__((always_inline)) {
    gll16(gB0 + (size_t)brow0 * 1024 + sk, &smem[wbu + AU + (w << 9)]);
  };
  auto stage_uBr = [&](int wbu, int sk) __attribute__((always_inline)) {
#pragma unroll
    for (int j = 0; j < NBR; ++j)
      gll16(gB0 + (size_t)browr_ld[j] * 1024 + sk,
            &smem[wbu + AU + 4096 + j * 4096 + (w << 9)]);
  };
  // A frag mf (phys): half k -> par = k*BM/2 + wm*QA + m*16 + lr
  auto rdAh = [&](int rbu, int half, bf16x8(&aa)[MF / 2][2])
      __attribute__((always_inline)) {
#pragma unroll
    for (int m = 0; m < MF / 2; ++m) {
      const int par = half * (BM / 2) + wm * QA + m * 16 + lr;
      const int base = rbu + par * 64;
      aa[m][0] = *(const bf16x8*)&smem[base + cx0];
      aa[m][1] = *(const bf16x8*)&smem[base + cx1];
    }
  };
  auto rdB0 = [&](int rbu) __attribute__((always_inline)) {
    const int pbr = wn * 16 + lr;
    const int base = rbu + AU + pbr * 64;
    b[0][0] = *(const bf16x8*)&smem[base + cx0];
    b[0][1] = *(const bf16x8*)&smem[base + cx1];
  };
  auto rdBr = [&](int rbu) __attribute__((always_inline)) {
#pragma unroll
    for (int n = 1; n < NF; ++n) {
      const int pbr = 64 + wn * (NF - 1) * 16 + (n - 1) * 16 + lr;
      const int base = rbu + AU + pbr * 64;
      b[n][0] = *(const bf16x8*)&smem[base + cx0];
      b[n][1] = *(const bf16x8*)&smem[base + cx1];
    }
  };
  auto mmg = [&](int mbase, int ng0, int ng1, bf16x8(&aa)[MF / 2][2])
      __attribute__((always_inline)) {
#pragma unroll
    for (int m = 0; m < MF / 2; ++m)
#pragma unroll
      for (int n = 0; n < NF; ++n) {
        if (n < ng0 || n >= ng1) continue;
        acc[mbase + m][n] = MFMA16(aa[m][0], b[n][0], acc[mbase + m][n]);
        acc[mbase + m][n] = MFMA16(aa[m][1], b[n][1], acc[mbase + m][n]);
      }
  };

  auto tile = [&](int rbu, int wbu, int sk, bool pf) __attribute__((always_inline)) {
    // ---- ph1: MFMA (mh0 x n0). Reads uA1+uB0 (confirmed at prev ph4).
    rdAh(rbu, 0, a0);
    rdB0(rbu);
    SCHED0;
    if (pf) {
      stage_uA1(wbu, sk);
      if constexpr (NA == 4) VMC(4); else VMC(2);  // confirm uBr(t)
    } else {
      if constexpr (NA == 4) VMC(2); else VMC(1);
    }
    SBAR();
    LGKM0;
    SCHED0;
    __builtin_amdgcn_s_setprio(1);
    mmg(0, 0, 1, a0);
    __builtin_amdgcn_s_setprio(0);
    SBAR();
    // ---- ph2: MFMA (mh0 x n1..). Reads uBr.
    rdBr(rbu);
    SCHED0;
    if (pf) {
      stage_uB0(wbu, sk);
      if constexpr (NA == 4) VMC(3); else VMC(2);  // confirm uA2(t)
    } else {
      VMC(0);
    }
    SBAR();
    LGKM0;
    SCHED0;
    __builtin_amdgcn_s_setprio(1);
    mmg(0, 1, NF, a0);
    __builtin_amdgcn_s_setprio(0);
    SBAR();
    // ---- ph3: MFMA (mh1 x n1..). Reads uA2.
    rdAh(rbu, 1, a1);
    SCHED0;
    if (pf) stage_uBr(wbu, sk);
    SBAR();
    LGKM0;
    SCHED0;
    __builtin_amdgcn_s_setprio(1);
    mmg(MF / 2, 1, NF, a1);
    __builtin_amdgcn_s_setprio(0);
    SBAR();
    // ---- ph4: MFMA (mh1 x n0). No reads (a1 from ph3, b0 from ph1).
    if (pf) {
      stage_uA2(wbu, sk);
      if constexpr (NA == 4) VMC(4); else VMC(2);  // confirm uA1,uB0(t+1)
    }
    SBAR();
    __builtin_amdgcn_s_setprio(1);
    mmg(MF / 2, 0, 1, a1);
    __builtin_amdgcn_s_setprio(0);
    SBAR();
  };

  // prologue: stage tile0 in FIFO unit order; confirm uA1+uB0.
  stage_uA1(0, 0);
  stage_uB0(0, 0);
  stage_uBr(0, 0);
  stage_uA2(0, 0);
  if constexpr (NA == 4) VMC(4); else VMC(2);
  SBAR();
  int sk = 64;
  for (int it = 0; it < 7; ++it) {
    tile(0, BUF, sk, true);
    sk += 64;
    tile(BUF, 0, sk, true);
    sk += 64;
  }
  tile(0, BUF, sk, true);   // t=14 stages tile 15
  tile(BUF, 0, 0, false);   // t=15: drain

  const size_t erow = (size_t)(m0 + wm * MF * 16 + hi * 4);
  const int ecol = n0 + wn * NF * 16 + lr;
#pragma unroll
  for (int mf = 0; mf < MF; ++mf)
#pragma unroll
    for (int nf = 0; nf < NF; ++nf)
#pragma unroll
      for (int r = 0; r < 4; ++r) {
        const size_t idx = (erow + mf * 16 + r) * LDC + ecol + nf * 16;
        if constexpr (F32OUT)
          ((float*)C)[idx] = acc[mf][nf][r];
        else
          ((ushort_t*)C)[idx] = f2bf(acc[mf][nf][r]);
      }
}

// Causal flash attention (REVERTED to R17 exact — verified ~38us).
__global__ __launch_bounds__(256, 2) void attn_fwd(const ushort_t* __restrict__ QKV,
                                                   ushort_t* __restrict__ ctx) {
  const int bid = blockIdx.x;
  const int h = bid & 15;
  const int b = (bid >> 4) & 7;
  const int p = bid >> 7;  // 0..3
  const int tid = threadIdx.x;
  const int lane = tid & 63;
  const int w = tid >> 6;
  const int lr = lane & 15;
  const int lg = lane >> 4;
  const int dk = lg << 3;

  __shared__ __attribute__((aligned(16))) ushort_t Ks[2][64 * 72];
  __shared__ __attribute__((aligned(16))) uint_t VtDw[2][64 * 36];

  const int kkey = tid >> 2, kdg = tid & 3;
  const int vkp = tid & 31, vdg = tid >> 5;
  const int pkp = ((vkp >> 4) << 4) | (((vkp >> 1) & 3) << 2) |
                  (((vkp >> 3) & 1) << 1) | (vkp & 1);
  const ushort_t* kgbase =
      QKV + ((size_t)(b * 1024 + kkey)) * 3072 + 1024 + h * 64 + kdg * 16;
  const ushort_t* vgbase =
      QKV + ((size_t)(b * 1024 + 2 * vkp)) * 3072 + 2048 + h * 64 + vdg * 8;

  const float FMAX2 = 23.083120654223414f;  // 16 * log2(e)

  const int qtA = p, qtB = 7 - p;
  const int ntB = (qtB + 1) << 1;
  const int wrow0A = (qtA << 7) + w * 32;
  const int wrow0B = (qtB << 7) + w * 32;

  bf16x8 qfA[2][2], qfB[2][2];
#pragma unroll
  for (int i = 0; i < 2; ++i) {
    const ushort_t* qpA =
        QKV + ((size_t)(b * 1024 + wrow0A + i * 16 + lr)) * 3072 + h * 64 + dk;
    qfA[i][0] = *reinterpret_cast<const bf16x8*>(qpA);
    qfA[i][1] = *reinterpret_cast<const bf16x8*>(qpA + 32);
    const ushort_t* qpB =
        QKV + ((size_t)(b * 1024 + wrow0B + i * 16 + lr)) * 3072 + h * 64 + dk;
    qfB[i][0] = *reinterpret_cast<const bf16x8*>(qpB);
    qfB[i][1] = *reinterpret_cast<const bf16x8*>(qpB + 32);
  }

  f32x4 oA[2][4] = {}, oB[2][4] = {};
  float lsA[2] = {0.f, 0.f}, lsB[2] = {0.f, 0.f};

  uint4 rk0 = *reinterpret_cast<const uint4*>(kgbase);
  uint4 rk1 = *reinterpret_cast<const uint4*>(kgbase + 8);
  uint2 rva = *reinterpret_cast<const uint2*>(vgbase);
  uint2 rvb = *reinterpret_cast<const uint2*>(vgbase + 4);
  uint2 rvc = *reinterpret_cast<const uint2*>(vgbase + 3072);
  uint2 rvd = *reinterpret_cast<const uint2*>(vgbase + 3072 + 4);

  for (int t = 0; t < ntB; ++t) {
    const int bsel = t & 1;
    asm volatile("s_waitcnt vmcnt(0)" ::: "memory");
    {
      uint_t* kd = reinterpret_cast<uint_t*>(&Ks[bsel][kkey * 72 + kdg * 16]);
      *reinterpret_cast<uint4*>(kd) = rk0;
      *reinterpret_cast<uint4*>(kd + 4) = rk1;
      const ushort_t* e0a = reinterpret_cast<const ushort_t*>(&rva);
      const ushort_t* e0b = reinterpret_cast<const ushort_t*>(&rvb);
      const ushort_t* e1a = reinterpret_cast<const ushort_t*>(&rvc);
      const ushort_t* e1b = reinterpret_cast<const ushort_t*>(&rvd);
#pragma unroll
      for (int j = 0; j < 4; ++j) {
        VtDw[bsel][(vdg * 8 + j) * 36 + pkp] = (uint_t)e0a[j] | ((uint_t)e1a[j] << 16);
        VtDw[bsel][(vdg * 8 + 4 + j) * 36 + pkp] =
            (uint_t)e0b[j] | ((uint_t)e1b[j] << 16);
      }
    }
    if (t + 1 < ntB) {
      const size_t off = (size_t)(t + 1) * 64 * 3072;
      rk0 = *reinterpret_cast<const uint4*>(kgbase + off);
      rk1 = *reinterpret_cast<const uint4*>(kgbase + off + 8);
      rva = *reinterpret_cast<const uint2*>(vgbase + off);
      rvb = *reinterpret_cast<const uint2*>(vgbase + off + 4);
      rvc = *reinterpret_cast<const uint2*>(vgbase + off + 3072);
      rvd = *reinterpret_cast<const uint2*>(vgbase + off + 3072 + 4);
    }
    asm volatile("s_waitcnt lgkmcnt(0)" ::: "memory");
    __builtin_amdgcn_s_barrier();

    const int kb = t << 6;
    const bool actB = (kb <= wrow0B + 31);
    const bool actA = (kb <= wrow0A + 31);
    if (!(actA || actB)) continue;

    bf16x8 kf0[4], kf1[4];
#pragma unroll
    for (int f = 0; f < 4; ++f) {
      kf0[f] = *reinterpret_cast<const bf16x8*>(&Ks[bsel][(f * 16 + lr) * 72 + dk]);
      kf1[f] =
          *reinterpret_cast<const bf16x8*>(&Ks[bsel][(f * 16 + lr) * 72 + 32 + dk]);
    }
    bf16x8 vb[2][4];
#pragma unroll
    for (int kblk = 0; kblk < 2; ++kblk)
#pragma unroll
      for (int fh = 0; fh < 4; ++fh)
        vb[kblk][fh] = *reinterpret_cast<const bf16x8*>(
            &VtDw[bsel][(fh * 16 + lr) * 36 + kblk * 16 + (lg << 2)]);

    auto group = [&](const bf16x8(&qf)[2][2], f32x4(&o)[2][4], float(&ls)[2],
                     int wrow0) __attribute__((always_inline)) {
      f32x4 s[2][4];
      __builtin_amdgcn_s_setprio(1);
#pragma unroll
      for (int i = 0; i < 2; ++i)
#pragma unroll
        for (int f = 0; f < 4; ++f) {
          f32x4 z = {0.f, 0.f, 0.f, 0.f};
          z = __builtin_amdgcn_mfma_f32_16x16x32_bf16(kf0[f], qf[i][0], z, 0, 0, 0);
          s[i][f] = __builtin_amdgcn_mfma_f32_16x16x32_bf16(kf1[f], qf[i][1], z, 0, 0, 0);
        }
      __builtin_amdgcn_s_setprio(0);
      const bool needmask = (kb + 63 > wrow0);
#pragma unroll
      for (int i = 0; i < 2; ++i) {
        const int qr = wrow0 + i * 16 + lr;
        uint_t d0[4], d1[4];
#pragma unroll
        for (int f = 0; f < 4; ++f) {
          const int kbase = kb + f * 16 + (lg << 2);
          float p0 = __builtin_amdgcn_exp2f(s[i][f][0] - FMAX2);
          float p1 = __builtin_amdgcn_exp2f(s[i][f][1] - FMAX2);
          float p2 = __builtin_amdgcn_exp2f(s[i][f][2] - FMAX2);
          float p3 = __builtin_amdgcn_exp2f(s[i][f][3] - FMAX2);
          if (needmask) {
            p0 = (kbase + 0 <= qr) ? p0 : 0.f;
            p1 = (kbase + 1 <= qr) ? p1 : 0.f;
            p2 = (kbase + 2 <= qr) ? p2 : 0.f;
            p3 = (kbase + 3 <= qr) ? p3 : 0.f;
          }
          ls[i] += (p0 + p1) + (p2 + p3);
          asm("v_cvt_pk_bf16_f32 %0, %1, %2" : "=v"(d0[f]) : "v"(p0), "v"(p1));
          asm("v_cvt_pk_bf16_f32 %0, %1, %2" : "=v"(d1[f]) : "v"(p2), "v"(p3));
        }
        __builtin_amdgcn_s_setprio(1);
#pragma unroll
        for (int kblk = 0; kblk < 2; ++kblk) {
          uint4 paw;
          paw.x = d0[2 * kblk];
          paw.y = d1[2 * kblk];
          paw.z = d0[2 * kblk + 1];
          paw.w = d1[2 * kblk + 1];
          const bf16x8 pa = __builtin_bit_cast(bf16x8, paw);
#pragma unroll
          for (int fh = 0; fh < 4; ++fh)
            o[i][fh] = __builtin_amdgcn_mfma_f32_16x16x32_bf16(pa, vb[kblk][fh],
                                                               o[i][fh], 0, 0, 0);
        }
        __builtin_amdgcn_s_setprio(0);
      }
    };

    if (actB) group(qfB, oB, lsB, wrow0B);
    if (actA) group(qfA, oA, lsA, wrow0A);
  }

  auto epi = [&](f32x4(&o)[2][4], float(&ls)[2], int wrow0)
      __attribute__((always_inline)) {
#pragma unroll
    for (int i = 0; i < 2; ++i) {
      float s = ls[i];
      s += __shfl_xor(s, 16);
      s += __shfl_xor(s, 32);
      const float linv = 1.0f / s;
      const size_t crow = (size_t)(b * 1024 + wrow0 + i * 16 + (lg << 2));
#pragma unroll
      for (int r = 0; r < 4; ++r) {
        const float li = __shfl(linv, (lg << 2) + r);
#pragma unroll
        for (int fh = 0; fh < 4; ++fh)
          ctx[(crow + r) * 1024 + h * 64 + fh * 16 + lr] = f2bf(o[i][fh][r] * li);
      }
    }
  };
  epi(oB, lsB, wrow0B);
  epi(oA, lsA, wrow0A);
}

extern "C" void kernel_launch(void* const* d_in, const int* in_sizes, int n_in,
                              void* d_out, int out_size, void* d_ws, size_t ws_size,
                              hipStream_t stream) {
  const float* x = (const float*)d_in[0];
  const float* Wk = (const float*)d_in[1];
  const float* Wq = (const float*)d_in[2];
  const float* Wv = (const float*)d_in[3];
  const float* Wo = (const float*)d_in[4];

  char* ws = (char*)d_ws;
  ushort_t* xb = (ushort_t*)ws;                  // [8192,1024] bf16 (reused as ctx)
  ushort_t* Wc = (ushort_t*)(ws + (16u << 20));  // Wq*0.125*log2e | Wk | Wv | Wo
  ushort_t* Wob = Wc + 3u * 1024 * 1024;
  ushort_t* QKV = (ushort_t*)(ws + (24u << 20));  // [8192,3072] bf16
  ushort_t* ctx = xb;

  cast_all<<<12288, 256, 0, stream>>>(x, Wq, Wk, Wv, Wo, xb, Wc,
                                      0.125f * 1.4426950408889634f);

  // QKV: BM=256, BN=192, per-unit pipelined schedule; 512 blocks = 2 full rounds.
  gemm8p<8, 3, 16, 3072, false><<<512, 512, 0, stream>>>(xb, Wc, QKV);

  attn_fwd<<<512, 256, 0, stream>>>(QKV, ctx);

  // Out-proj: BM=128, BN=128; 512 blocks = 1 full round at 2/CU.
  gemm8p<4, 2, 8, 1024, true><<<512, 512, 0, stream>>>(ctx, Wob, (float*)d_out);
}